// Round 1
// baseline (278.556 us; speedup 1.0000x reference)
//
#include <hip/hip_runtime.h>
#include <math.h>

// Problem constants
#define H   2048
#define NB  8192
#define KCH 32          // chunks along H
#define LCH 64          // steps per chunk (H / KCH)
#define BPC 32          // blocks per chunk (NB / 256)

// Model constants
// DT = 0.05, WHEELBASE = 2.5, MAX_STEER = 0.5, MAX_ACC = 5.0
#define DT_F 0.05f

// ---------------------------------------------------------------------------
// Kernel A: per-step constant scans (single block, 256 threads x 8 elems).
//   dv_j = DT*MAX_ACC*clip(a_j, -1, 1)
//   w_j  = (DT/WHEELBASE)*tan(clip(s_j, -0.5, 0.5))
//   C_i  = exclusive prefix of dv   (speed_i = s0 + C_i)
//   A_i  = exclusive prefix of w    (yaw_i = yaw0 + s0*A_i + B_i)
//   B_i  = exclusive prefix of C_j*w_j
// Double-precision accumulation; controls index j runs 0..H-2 (last unused).
// ---------------------------------------------------------------------------
__global__ __launch_bounds__(256) void precomp_scan(
    const float* __restrict__ accel, const float* __restrict__ steering,
    float* __restrict__ Cv, float* __restrict__ Av, float* __restrict__ Bv) {
  __shared__ double lds[256];
  const int t = threadIdx.x;

  double dv[8], w[8], Cl[8];
  for (int m = 0; m < 8; ++m) {
    int j = t * 8 + m;
    if (j < H - 1) {
      float a = accel[j];    a = fminf(1.0f, fmaxf(-1.0f, a));
      float s = steering[j]; s = fminf(0.5f, fmaxf(-0.5f, s));
      dv[m] = 0.25 * (double)a;          // DT * MAX_ACC = 0.05 * 5.0
      w[m]  = 0.02 * tan((double)s);     // DT / WHEELBASE = 0.05 / 2.5
    } else {
      dv[m] = 0.0; w[m] = 0.0;
    }
  }

  // --- scan 1: dv -> C (exclusive), keep Cl in regs ---
  {
    double tot = 0.0;
    for (int m = 0; m < 8; ++m) tot += dv[m];
    double run = tot; lds[t] = run; __syncthreads();
    for (int off = 1; off < 256; off <<= 1) {
      double y = (t >= off) ? lds[t - off] : 0.0;
      __syncthreads();
      run += y; lds[t] = run; __syncthreads();
    }
    double e = run - tot;
    for (int m = 0; m < 8; ++m) { Cl[m] = e; Cv[t * 8 + m] = (float)e; e += dv[m]; }
  }
  __syncthreads();

  // --- scan 2: w -> A (exclusive) ---
  {
    double tot = 0.0;
    for (int m = 0; m < 8; ++m) tot += w[m];
    double run = tot; lds[t] = run; __syncthreads();
    for (int off = 1; off < 256; off <<= 1) {
      double y = (t >= off) ? lds[t - off] : 0.0;
      __syncthreads();
      run += y; lds[t] = run; __syncthreads();
    }
    double e = run - tot;
    for (int m = 0; m < 8; ++m) { Av[t * 8 + m] = (float)e; e += w[m]; }
  }
  __syncthreads();

  // --- scan 3: C*w -> B (exclusive) ---
  {
    double v[8];
    for (int m = 0; m < 8; ++m) v[m] = Cl[m] * w[m];
    double tot = 0.0;
    for (int m = 0; m < 8; ++m) tot += v[m];
    double run = tot; lds[t] = run; __syncthreads();
    for (int off = 1; off < 256; off <<= 1) {
      double y = (t >= off) ? lds[t - off] : 0.0;
      __syncthreads();
      run += y; lds[t] = run; __syncthreads();
    }
    double e = run - tot;
    for (int m = 0; m < 8; ++m) { Bv[t * 8 + m] = (float)e; e += v[m]; }
  }
}

// ---------------------------------------------------------------------------
// Kernel B: closed-form yaw/speed outputs + per-chunk partial sums of
// speed*cos(yaw), speed*sin(yaw) for the x/y scans.
// Grid: KCH * BPC blocks of 256; block -> (chunk k, 256 consecutive rollouts).
// ---------------------------------------------------------------------------
__global__ __launch_bounds__(256) void yaw_speed_partials(
    const float* __restrict__ syaw, const float* __restrict__ sspd,
    const float* __restrict__ Cv, const float* __restrict__ Av,
    const float* __restrict__ Bv,
    float* __restrict__ out, float* __restrict__ px, float* __restrict__ py) {
  __shared__ float sC[LCH], sA[LCH], sB[LCH];
  const int k  = blockIdx.x >> 5;                       // / BPC
  const int b  = ((blockIdx.x & (BPC - 1)) << 8) + threadIdx.x;
  const int j0 = k * LCH;
  if (threadIdx.x < LCH) {
    sC[threadIdx.x] = Cv[j0 + threadIdx.x];
    sA[threadIdx.x] = Av[j0 + threadIdx.x];
    sB[threadIdx.x] = Bv[j0 + threadIdx.x];
  }
  __syncthreads();

  const float yaw0 = syaw[b];
  const float s0   = sspd[b];
  float accx = 0.0f, accy = 0.0f;
  float* __restrict__ oy = out + 2 * (size_t)H * NB;
  float* __restrict__ os = out + 3 * (size_t)H * NB;

  for (int m = 0; m < LCH; ++m) {
    float speed = s0 + sC[m];
    float yaw   = fmaf(s0, sA[m], yaw0) + sB[m];
    float sn, cs;
    __sincosf(yaw, &sn, &cs);
    size_t idx = (size_t)(j0 + m) * NB + b;
    oy[idx] = yaw;
    os[idx] = speed;
    accx = fmaf(speed, cs, accx);
    accy = fmaf(speed, sn, accy);
  }
  px[k * NB + b] = accx;
  py[k * NB + b] = accy;
}

// ---------------------------------------------------------------------------
// Kernel C: exclusive scan over KCH chunk partials, per rollout.
// ---------------------------------------------------------------------------
__global__ __launch_bounds__(256) void chunk_scan(
    const float* __restrict__ px, const float* __restrict__ py,
    float* __restrict__ ox, float* __restrict__ oyv) {
  const int b = blockIdx.x * 256 + threadIdx.x;
  float ax = 0.0f, ay = 0.0f;
  for (int k = 0; k < KCH; ++k) {
    float tx = px[k * NB + b];
    float ty = py[k * NB + b];
    ox[k * NB + b]  = ax;
    oyv[k * NB + b] = ay;
    ax += tx;
    ay += ty;
  }
}

// ---------------------------------------------------------------------------
// Kernel D: x/y outputs. Running prefix starts at the chunk offset; within
// the chunk, re-derive speed/yaw in closed form and recompute sincos
// (cheaper than 128 MiB of extra HBM traffic).
// ---------------------------------------------------------------------------
__global__ __launch_bounds__(256) void xy_write(
    const float* __restrict__ sx, const float* __restrict__ sy,
    const float* __restrict__ syaw, const float* __restrict__ sspd,
    const float* __restrict__ Cv, const float* __restrict__ Av,
    const float* __restrict__ Bv,
    const float* __restrict__ ox, const float* __restrict__ oyv,
    float* __restrict__ out) {
  __shared__ float sC[LCH], sA[LCH], sB[LCH];
  const int k  = blockIdx.x >> 5;
  const int b  = ((blockIdx.x & (BPC - 1)) << 8) + threadIdx.x;
  const int j0 = k * LCH;
  if (threadIdx.x < LCH) {
    sC[threadIdx.x] = Cv[j0 + threadIdx.x];
    sA[threadIdx.x] = Av[j0 + threadIdx.x];
    sB[threadIdx.x] = Bv[j0 + threadIdx.x];
  }
  __syncthreads();

  const float x0   = sx[b];
  const float y0   = sy[b];
  const float yaw0 = syaw[b];
  const float s0   = sspd[b];
  float rx = ox[k * NB + b];
  float ry = oyv[k * NB + b];
  float* __restrict__ outx = out;
  float* __restrict__ outy = out + (size_t)H * NB;

  for (int m = 0; m < LCH; ++m) {
    float speed = s0 + sC[m];
    float yaw   = fmaf(s0, sA[m], yaw0) + sB[m];
    float sn, cs;
    __sincosf(yaw, &sn, &cs);
    size_t idx = (size_t)(j0 + m) * NB + b;
    outx[idx] = fmaf(DT_F, rx, x0);
    outy[idx] = fmaf(DT_F, ry, y0);
    rx = fmaf(speed, cs, rx);
    ry = fmaf(speed, sn, ry);
  }
}

// ---------------------------------------------------------------------------
extern "C" void kernel_launch(void* const* d_in, const int* in_sizes, int n_in,
                              void* d_out, int out_size, void* d_ws, size_t ws_size,
                              hipStream_t stream) {
  const float* start_x     = (const float*)d_in[0];
  const float* start_y     = (const float*)d_in[1];
  const float* start_yaw   = (const float*)d_in[2];
  const float* start_speed = (const float*)d_in[3];
  const float* accel       = (const float*)d_in[4];
  const float* steering    = (const float*)d_in[5];
  float* out = (float*)d_out;

  // Workspace layout (floats):
  //   [0, H)        C   (speed offsets)
  //   [H, 2H)       A   (yaw slope vs s0)
  //   [2H, 3H)      B   (yaw constant)
  //   then px, py, ox, oy, each KCH*NB
  float* ws = (float*)d_ws;
  float* Cv  = ws;
  float* Av  = ws + H;
  float* Bv  = ws + 2 * H;
  float* px  = ws + 3 * H;
  float* py  = px + (size_t)KCH * NB;
  float* ox  = py + (size_t)KCH * NB;
  float* oyv = ox + (size_t)KCH * NB;

  precomp_scan<<<1, 256, 0, stream>>>(accel, steering, Cv, Av, Bv);
  yaw_speed_partials<<<KCH * BPC, 256, 0, stream>>>(start_yaw, start_speed,
                                                    Cv, Av, Bv, out, px, py);
  chunk_scan<<<NB / 256, 256, 0, stream>>>(px, py, ox, oyv);
  xy_write<<<KCH * BPC, 256, 0, stream>>>(start_x, start_y, start_yaw, start_speed,
                                          Cv, Av, Bv, ox, oyv, out);
}